// Round 8
// baseline (1021.101 us; speedup 1.0000x reference)
//
#include <hip/hip_runtime.h>
#include <hip/hip_bf16.h>

typedef __hip_bfloat16 bf16;
typedef __attribute__((ext_vector_type(8))) short short8;   // 8 bf16 (4 VGPRs)
typedef __attribute__((ext_vector_type(4))) float f32x4;    // MFMA accumulator

#define MFMA16(a, b, c) __builtin_amdgcn_mfma_f32_16x16x32_bf16((a), (b), (c), 0, 0, 0)

// dual-mode float load: f32 ? float buffer : bf16 buffer (same element index)
static __device__ __forceinline__ float ldf(const void* p, long long i, bool f32) {
    return f32 ? ((const float*)p)[i] : __bfloat162float(((const bf16*)p)[i]);
}

// ---------------------------------------------------------------- encoding sniffer
// flags[0]: x is fp32?  flags[1]: weights are fp32?  flags[2]: edge_index is int64?
// MEASURED (R5-R7 counters): x=bf16, weights=fp32, out=bf16 on this harness.
__global__ __launch_bounds__(256, 4)
void sniff_kernel(const void* __restrict__ x, const void* __restrict__ w,
                  const int* __restrict__ ei, int E, int* __restrict__ flags) {
    __shared__ int cnt;
    if (threadIdx.x == 0) cnt = 0;
    __syncthreads();
    if (blockIdx.x < 2) {
        const unsigned short* u = (const unsigned short*)(blockIdx.x == 0 ? x : w);
        int bad = 0;
        for (int i = threadIdx.x; i < 4096; i += 256) {
            unsigned e = (u[i] >> 7) & 0xFF;
            if (e >= 0xA0) bad++;
        }
        atomicAdd(&cnt, bad);
        __syncthreads();
        if (threadIdx.x == 0) flags[blockIdx.x] = (cnt > 16) ? 1 : 0;
    } else {
        int nz = 0;
        for (int i = threadIdx.x; i < 1024; i += 256)
            if (ei[2 * i + 1] != 0) nz++;
        atomicAdd(&cnt, nz);
        __syncthreads();
        if (threadIdx.x == 0) flags[2] = (cnt == 0) ? 1 : 0;
    }
}

static __device__ __forceinline__ int ld_src(const int* ei, int E, int e, bool i64) {
    return i64 ? ei[2 * e] : ei[e];
}
static __device__ __forceinline__ int ld_dst(const int* ei, int E, int e, bool i64) {
    return i64 ? ei[2 * (E + e)] : ei[E + e];
}

// ---------------------------------------------------------------- degree counts (int)
__global__ __launch_bounds__(256, 4)
void count_kernel(const int* __restrict__ ei, int E, const int* __restrict__ flags,
                  int* __restrict__ counts) {
    int i = blockIdx.x * blockDim.x + threadIdx.x;
    if (i >= E) return;
    bool i64 = flags[2] != 0;
    atomicAdd(&counts[ld_dst(ei, E, i, i64)], 1);
}

__global__ __launch_bounds__(256, 4)
void dinv_kernel(const int* __restrict__ counts, float* __restrict__ dinv, int N) {
    int i = blockIdx.x * blockDim.x + threadIdx.x;
    if (i < N) dinv[i] = rsqrtf((float)counts[i] + 1.0f);
}

// ---------------------------------------------------------------- exclusive scan (single block)
__global__ __launch_bounds__(256, 4)
void scan_kernel(const int* __restrict__ counts, int* __restrict__ rowptr, int N) {
    __shared__ int bs[256];
    const int T = 256;
    int chunk = (N + T - 1) / T;
    int lo = threadIdx.x * chunk;
    int hi = lo + chunk; if (hi > N) hi = N; if (lo > N) lo = N;
    int sum = 0;
    for (int i = lo; i < hi; i++) sum += counts[i];
    bs[threadIdx.x] = sum;
    __syncthreads();
    for (int off = 1; off < T; off <<= 1) {
        int t = 0;
        if ((int)threadIdx.x >= off) t = bs[threadIdx.x - off];
        __syncthreads();
        if ((int)threadIdx.x >= off) bs[threadIdx.x] += t;
        __syncthreads();
    }
    int run = bs[threadIdx.x] - sum;
    for (int i = lo; i < hi; i++) { rowptr[i] = run; run += counts[i]; }
    if (hi == N && lo < N) rowptr[N] = run;
    if (N == 0 && threadIdx.x == 0) rowptr[0] = 0;
}

// ---------------------------------------------------------------- CSR fill (counting sort by dst)
__global__ __launch_bounds__(256, 4)
void fill_kernel(const int* __restrict__ ei, int E, const int* __restrict__ flags,
                 const int* __restrict__ rowptr, int* __restrict__ cursor,
                 int* __restrict__ csr_src) {
    int e = blockIdx.x * blockDim.x + threadIdx.x;
    if (e >= E) return;
    bool i64 = flags[2] != 0;
    int s = ld_src(ei, E, e, i64), d = ld_dst(ei, E, e, i64);
    int p = atomicAdd(&cursor[d], 1);
    csr_src[rowptr[d] + p] = s;
}

// ---------------------------------------------------------------- weight -> MFMA B-fragment packs
// frag f = kstep*ntiles + ntile; slot s = f*64 + lane; element j (0..7):
//   W[kstep*32 + (lane>>4)*8 + j][ntile*16 + (lane&15)]
// Converts fp32 OR bf16 weights to bf16 fragments (fw-aware).
__global__ __launch_bounds__(256, 4)
void repack_kernel(const void* __restrict__ W1, const void* __restrict__ W2,
                   const void* __restrict__ Wl, const int* __restrict__ flags,
                   bf16* __restrict__ Bp1, bf16* __restrict__ Bp2, bf16* __restrict__ Bp3) {
    bool fw = flags[1] != 0;
    const void* W; bf16* Bp; int ntiles, nc, nfrag;
    if (blockIdx.x == 0)      { W = W1; Bp = Bp1; ntiles = 4; nc = 64; nfrag = 16; }
    else if (blockIdx.x == 1) { W = W2; Bp = Bp2; ntiles = 2; nc = 32; nfrag = 4;  }
    else                      { W = Wl; Bp = Bp3; ntiles = 2; nc = 32; nfrag = 14; }
    for (int s = threadIdx.x; s < nfrag * 64; s += 256) {
        int f = s >> 6, lane = s & 63;
        int kstep = f / ntiles, ntile = f % ntiles;
        int n = ntile * 16 + (lane & 15);
        int kbase = kstep * 32 + (lane >> 4) * 8;
#pragma unroll
        for (int j = 0; j < 8; j++)
            Bp[s * 8 + j] = __float2bfloat16(ldf(W, (long long)(kbase + j) * nc + n, fw));
    }
}

// ---------------------------------------------------------------- GEMM1 (MFMA — runs whenever x is bf16)
__global__ __launch_bounds__(256, 3)
void gemm1_mfma_kernel(const short* __restrict__ x, const bf16* __restrict__ Bpack,
                       const int* __restrict__ flags, float* __restrict__ h1x, int N) {
    if (flags[0] != 0) return;   // x fp32 -> fallback kernel
    int lane = threadIdx.x & 63, wave = threadIdx.x >> 6;
    int m = lane & 15, quad = lane >> 4;
    int base = blockIdx.x * 128 + wave * 32;
    const short8* bp = (const short8*)Bpack;
    short8 B[16];
#pragma unroll
    for (int i = 0; i < 16; i++) B[i] = bp[i * 64 + lane];
    if (base + 32 <= N) {
#pragma unroll
        for (int t = 0; t < 2; t++) {
            int r0 = base + t * 16;
            const short* xr = &x[(long long)(r0 + m) * 128 + quad * 8];
            short8 A[4];
#pragma unroll
            for (int k = 0; k < 4; k++) A[k] = *(const short8*)(xr + k * 32);
            f32x4 acc[4];
#pragma unroll
            for (int nt = 0; nt < 4; nt++) acc[nt] = (f32x4){0.f, 0.f, 0.f, 0.f};
#pragma unroll
            for (int k = 0; k < 4; k++) {
#pragma unroll
                for (int nt = 0; nt < 4; nt++) acc[nt] = MFMA16(A[k], B[k * 4 + nt], acc[nt]);
            }
            float* o = &h1x[(long long)(r0 + quad * 4) * 64 + m];
#pragma unroll
            for (int nt = 0; nt < 4; nt++) {
#pragma unroll
                for (int r = 0; r < 4; r++) o[(long long)r * 64 + nt * 16] = acc[nt][r];
            }
        }
    } else if (base < N) {
#pragma unroll
        for (int t = 0; t < 2; t++) {
            int r0 = base + t * 16;
            int row = r0 + m;
            short8 A[4];
#pragma unroll
            for (int k = 0; k < 4; k++) A[k] = (short8){0,0,0,0,0,0,0,0};
            if (row < N) {
                const short* xr = &x[(long long)row * 128 + quad * 8];
#pragma unroll
                for (int k = 0; k < 4; k++) A[k] = *(const short8*)(xr + k * 32);
            }
            f32x4 acc[4];
#pragma unroll
            for (int nt = 0; nt < 4; nt++) acc[nt] = (f32x4){0.f, 0.f, 0.f, 0.f};
#pragma unroll
            for (int k = 0; k < 4; k++) {
#pragma unroll
                for (int nt = 0; nt < 4; nt++) acc[nt] = MFMA16(A[k], B[k * 4 + nt], acc[nt]);
            }
#pragma unroll
            for (int r = 0; r < 4; r++) {
                int orow = r0 + quad * 4 + r;
                if (orow < N) {
                    float* o = &h1x[(long long)orow * 64 + m];
#pragma unroll
                    for (int nt = 0; nt < 4; nt++) o[nt * 16] = acc[nt][r];
                }
            }
        }
    }
}

// ---------------------------------------------------------------- GEMM1 fallback (x fp32 only)
__global__ __launch_bounds__(256, 4)
void gemm1_fallback_kernel(const void* __restrict__ x, const void* __restrict__ W1,
                           const int* __restrict__ flags, float* __restrict__ h1x, int N) {
    if (flags[0] == 0) return;   // x bf16 -> MFMA kernel
    __shared__ float Ws[128 * 64];
    __shared__ float Xs[4 * 128];
    bool fx = flags[0] != 0, fw = flags[1] != 0;
    for (int i = threadIdx.x; i < 128 * 64; i += 256) Ws[i] = ldf(W1, i, fw);
    int base = blockIdx.x * 4;
    for (int i = threadIdx.x; i < 4 * 128; i += 256) {
        int r = i >> 7, k = i & 127;
        int n = base + r;
        Xs[i] = (n < N) ? ldf(x, (long long)n * 128 + k, fx) : 0.f;
    }
    __syncthreads();
    int ln = threadIdx.x >> 6, c = threadIdx.x & 63;
    int n = base + ln;
    if (n >= N) return;
    float acc = 0.f;
    const float* xr = &Xs[ln * 128];
#pragma unroll 8
    for (int k = 0; k < 128; k++) acc = fmaf(xr[k], Ws[k * 64 + c], acc);
    h1x[(long long)n * 64 + c] = acc;
}

// ---------------------------------------------------------------- gather layer 1
// bf16-x mode: writes h1b (bf16). fp32-x mode: writes h1 (f32).
__global__ __launch_bounds__(256, 4)
void gather1_kernel(const float* __restrict__ h1x, const float* __restrict__ dinv,
                    const int* __restrict__ rowptr, const int* __restrict__ csr_src,
                    const void* __restrict__ b1, const int* __restrict__ flags,
                    float* __restrict__ h1, bf16* __restrict__ h1b, int N) {
    bool fw = flags[1] != 0, bfmode = flags[0] == 0;
    int lane = threadIdx.x & 63;
    int node = blockIdx.x * 4 + (threadIdx.x >> 6);
    if (node >= N) return;
    int beg = rowptr[node], end = rowptr[node + 1];
    float dvd = dinv[node];
    float acc = 0.f;
    for (int b = beg; b < end; b += 64) {
        int cnt = end - b; if (cnt > 64) cnt = 64;
        int s = 0; float dvs = 0.f;
        if (lane < cnt) { s = csr_src[b + lane]; dvs = dinv[s]; }
        for (int j = 0; j < cnt; j++) {
            int sj = __shfl(s, j);
            float nm = __shfl(dvs, j) * dvd;
            acc = fmaf(h1x[(long long)sj * 64 + lane], nm, acc);
        }
    }
    float v = acc + h1x[(long long)node * 64 + lane] * (dvd * dvd) + ldf(b1, lane, fw);
    v = fmaxf(v, 0.f);
    if (bfmode) h1b[(long long)node * 64 + lane] = __float2bfloat16(v);
    else        h1 [(long long)node * 64 + lane] = v;
}

// ---------------------------------------------------------------- GEMM2 (MFMA, bf16-x mode): h1b[N,64]@W2 -> h2x[N,32]
__global__ __launch_bounds__(256, 4)
void gemm2_mfma_kernel(const short* __restrict__ h1b, const bf16* __restrict__ Bpack,
                       const int* __restrict__ flags, float* __restrict__ h2x, int N) {
    if (flags[0] != 0) return;
    int lane = threadIdx.x & 63, wave = threadIdx.x >> 6;
    int m = lane & 15, quad = lane >> 4;
    int r0 = blockIdx.x * 64 + wave * 16;
    if (r0 >= N) return;
    const short8* bp = (const short8*)Bpack;
    short8 B[4];
#pragma unroll
    for (int i = 0; i < 4; i++) B[i] = bp[i * 64 + lane];
    f32x4 acc0 = {0.f,0.f,0.f,0.f}, acc1 = {0.f,0.f,0.f,0.f};
    if (r0 + 16 <= N) {
        const short* xr = &h1b[(long long)(r0 + m) * 64 + quad * 8];
#pragma unroll
        for (int k = 0; k < 2; k++) {
            short8 A = *(const short8*)(xr + k * 32);
            acc0 = MFMA16(A, B[k * 2 + 0], acc0);
            acc1 = MFMA16(A, B[k * 2 + 1], acc1);
        }
        float* o = &h2x[(long long)(r0 + quad * 4) * 32 + m];
#pragma unroll
        for (int r = 0; r < 4; r++) { o[(long long)r * 32] = acc0[r]; o[(long long)r * 32 + 16] = acc1[r]; }
    } else {
        int row = r0 + m;
#pragma unroll
        for (int k = 0; k < 2; k++) {
            short8 A = {0,0,0,0,0,0,0,0};
            if (row < N) A = *(const short8*)&h1b[(long long)row * 64 + k * 32 + quad * 8];
            acc0 = MFMA16(A, B[k * 2 + 0], acc0);
            acc1 = MFMA16(A, B[k * 2 + 1], acc1);
        }
#pragma unroll
        for (int r = 0; r < 4; r++) {
            int orow = r0 + quad * 4 + r;
            if (orow < N) {
                h2x[(long long)orow * 32 + m] = acc0[r];
                h2x[(long long)orow * 32 + 16 + m] = acc1[r];
            }
        }
    }
}

// ---------------------------------------------------------------- gather layer 2 (bf16-x mode): h2x -> h2b
__global__ __launch_bounds__(256, 4)
void gather2_kernel(const float* __restrict__ h2x, const float* __restrict__ dinv,
                    const int* __restrict__ rowptr, const int* __restrict__ csr_src,
                    const void* __restrict__ b2, const int* __restrict__ flags,
                    bf16* __restrict__ h2b, int N) {
    if (flags[0] != 0) return;
    bool fw = flags[1] != 0;
    int j = threadIdx.x & 31;
    int node = blockIdx.x * 8 + (threadIdx.x >> 5);
    if (node >= N) return;
    int beg = rowptr[node], end = rowptr[node + 1];
    float dvd = dinv[node];
    float acc = 0.f;
    for (int b = beg; b < end; b += 32) {
        int cnt = end - b; if (cnt > 32) cnt = 32;
        int s = 0; float dvs = 0.f;
        if (j < cnt) { s = csr_src[b + j]; dvs = dinv[s]; }
        for (int jj = 0; jj < cnt; jj++) {
            int sj = __shfl(s, jj, 32);
            float nm = __shfl(dvs, jj, 32) * dvd;
            acc = fmaf(h2x[(long long)sj * 32 + j], nm, acc);
        }
    }
    acc += h2x[(long long)node * 32 + j] * (dvd * dvd) + ldf(b2, j, fw);
    h2b[(long long)node * 32 + j] = __float2bfloat16(acc);
}

// ---------------------------------------------------------------- final (MFMA, bf16-x mode)
__global__ __launch_bounds__(256, 2)
void final_mfma_kernel(const short* __restrict__ x, const short* __restrict__ h1b,
                       const short* __restrict__ h2b, const bf16* __restrict__ Bpack,
                       const void* __restrict__ bl, const int* __restrict__ flags,
                       bf16* __restrict__ out, int N) {
    if (flags[0] != 0) return;
    bool fw = flags[1] != 0;   // bias may be fp32 even in bf16-x mode
    int lane = threadIdx.x & 63, wave = threadIdx.x >> 6;
    int m = lane & 15, quad = lane >> 4;
    int r0 = blockIdx.x * 64 + wave * 16;
    if (r0 >= N) return;
    const short8* bp = (const short8*)Bpack;
    short8 B[14];
#pragma unroll
    for (int i = 0; i < 14; i++) B[i] = bp[i * 64 + lane];
    f32x4 acc0 = {0.f,0.f,0.f,0.f}, acc1 = {0.f,0.f,0.f,0.f};
    bool full = (r0 + 16 <= N);
    int row = r0 + m;
    bool rowok = full || (row < N);
#pragma unroll
    for (int s = 0; s < 7; s++) {
        short8 A = {0,0,0,0,0,0,0,0};
        if (rowok) {
            const short* p;
            if (s < 4)      p = &x  [(long long)row * 128 + s * 32 + quad * 8];
            else if (s < 6) p = &h1b[(long long)row * 64 + (s - 4) * 32 + quad * 8];
            else            p = &h2b[(long long)row * 32 + quad * 8];
            A = *(const short8*)p;
        }
        acc0 = MFMA16(A, B[s * 2 + 0], acc0);
        acc1 = MFMA16(A, B[s * 2 + 1], acc1);
    }
    float bl0 = ldf(bl, m, fw), bl1 = ldf(bl, m + 16, fw);
#pragma unroll
    for (int r = 0; r < 4; r++) {
        float v0 = acc0[r] + bl0, v1 = acc1[r] + bl1;
        float mx = fmaxf(v0, v1);
#pragma unroll
        for (int o = 8; o > 0; o >>= 1) mx = fmaxf(mx, __shfl_xor(mx, o));
        float sm = __expf(v0 - mx) + __expf(v1 - mx);
#pragma unroll
        for (int o = 8; o > 0; o >>= 1) sm += __shfl_xor(sm, o);
        float lse = mx + __logf(sm);
        int orow = r0 + quad * 4 + r;
        if (orow < N) {
            out[(long long)orow * 32 + m]      = __float2bfloat16(v0 - lse);
            out[(long long)orow * 32 + 16 + m] = __float2bfloat16(v1 - lse);
        }
    }
}

// ---------------------------------------------------------------- GEMM2 fallback (x fp32 mode)
__global__ __launch_bounds__(256, 4)
void gemm2_kernel(const float* __restrict__ h1, const void* __restrict__ W2,
                  const int* __restrict__ flags, float* __restrict__ h2x, int N) {
    if (flags[0] == 0) return;
    __shared__ float Ws[64 * 32];
    __shared__ float Xs[8 * 64];
    bool fw = flags[1] != 0;
    for (int i = threadIdx.x; i < 64 * 32; i += 256) Ws[i] = ldf(W2, i, fw);
    int base = blockIdx.x * 8;
    for (int i = threadIdx.x; i < 8 * 64; i += 256) {
        int r = i >> 6, k = i & 63;
        int n = base + r;
        Xs[i] = (n < N) ? h1[(long long)n * 64 + k] : 0.f;
    }
    __syncthreads();
    int ln = threadIdx.x >> 5, c = threadIdx.x & 31;
    int n = base + ln;
    if (n >= N) return;
    float acc = 0.f;
    const float* xr = &Xs[ln * 64];
#pragma unroll 8
    for (int k = 0; k < 64; k++) acc = fmaf(xr[k], Ws[k * 32 + c], acc);
    h2x[(long long)n * 32 + c] = acc;
}

// ---------------------------------------------------------------- final fallback (x fp32 mode)
__global__ __launch_bounds__(256, 4)
void final_kernel(const void* __restrict__ x, const float* __restrict__ h1,
                  const float* __restrict__ h2x, const float* __restrict__ dinv,
                  const int* __restrict__ rowptr, const int* __restrict__ csr_src,
                  const void* __restrict__ b2, const void* __restrict__ Wl,
                  const void* __restrict__ bl, const int* __restrict__ flags,
                  void* __restrict__ out, int N) {
    if (flags[0] == 0) return;
    __shared__ float Ws[224 * 32];
    __shared__ float Cs[8 * 224];
    bool fx = flags[0] != 0, fw = flags[1] != 0;
    for (int i = threadIdx.x; i < 224 * 32; i += 256) Ws[i] = ldf(Wl, i, fw);
    int base = blockIdx.x * 8;
    for (int i = threadIdx.x; i < 8 * 192; i += 256) {
        int r = i / 192, k = i % 192;
        int n = base + r;
        float v = 0.f;
        if (n < N) v = (k < 128) ? ldf(x, (long long)n * 128 + k, fx)
                                 : h1[(long long)n * 64 + (k - 128)];
        Cs[r * 224 + k] = v;
    }
    int g = threadIdx.x >> 5, j = threadIdx.x & 31;
    int n = base + g;
    if (n < N) {
        float dvd = dinv[n];
        int beg = rowptr[n], end = rowptr[n + 1];
        float acc = 0.f;
        for (int b = beg; b < end; b += 32) {
            int cnt = end - b; if (cnt > 32) cnt = 32;
            int s = 0; float dvs = 0.f;
            if (j < cnt) { s = csr_src[b + j]; dvs = dinv[s]; }
            for (int jj = 0; jj < cnt; jj++) {
                int sj = __shfl(s, jj, 32);
                float nm = __shfl(dvs, jj, 32) * dvd;
                acc = fmaf(h2x[(long long)sj * 32 + j], nm, acc);
            }
        }
        acc += h2x[(long long)n * 32 + j] * (dvd * dvd) + ldf(b2, j, fw);
        Cs[g * 224 + 192 + j] = acc;
    }
    __syncthreads();
    float acc = ldf(bl, j, fw);
    const float* cr = &Cs[g * 224];
#pragma unroll 8
    for (int k = 0; k < 224; k++) acc = fmaf(cr[k], Ws[k * 32 + j], acc);
    float m = acc;
    for (int o = 16; o > 0; o >>= 1) m = fmaxf(m, __shfl_xor(m, o, 32));
    float ex = __expf(acc - m);
    float s = ex;
    for (int o = 16; o > 0; o >>= 1) s += __shfl_xor(s, o, 32);
    float r = acc - m - __logf(s);
    if (n < N) {
        if (fx) ((float*)out)[(long long)n * 32 + j] = r;
        else    ((bf16*)out)[(long long)n * 32 + j] = __float2bfloat16(r);
    }
}

extern "C" void kernel_launch(void* const* d_in, const int* in_sizes, int n_in,
                              void* d_out, int out_size, void* d_ws, size_t ws_size,
                              hipStream_t stream) {
    const void* x  = d_in[0];
    const int*  ei = (const int*)d_in[1];
    const void* W1 = d_in[2];
    const void* b1 = d_in[3];
    const void* W2 = d_in[4];
    const void* b2 = d_in[5];
    const void* Wl = d_in[6];
    const void* bl = d_in[7];

    int N = in_sizes[0] / 128;
    int E = in_sizes[1] / 2;

    // ws layout (4B units):
    // [flags 16 | counts N | cursor N | dinv N | rowptr N+16 | Bp1 4096 | Bp2 1024 | Bp3 3584 |
    //  csr_src E | h1x N*64 (h2x aliases) | U N*64]
    int* ip      = (int*)d_ws;
    int* flags   = ip;
    int* counts  = ip + 16;
    int* cursor  = counts + N;
    float* dinv  = (float*)(cursor + N);
    int* rowptr  = (int*)(dinv + N);
    bf16* Bp1    = (bf16*)(rowptr + N + 16);
    bf16* Bp2    = (bf16*)((int*)Bp1 + 4096);
    bf16* Bp3    = (bf16*)((int*)Bp2 + 1024);
    int* csr_src = (int*)Bp3 + 3584;
    float* h1x   = (float*)(csr_src + E);
    int*   U     = (int*)(h1x + (size_t)N * 64);
    float* h1    = (float*)U;                     // fp32-x mode
    bf16*  h1b   = (bf16*)U;                      // bf16-x mode
    bf16*  h2b   = (bf16*)(U + (size_t)N * 32);   // bf16-x mode
    float* h2x   = h1x;                           // alias (h1x dead after gather1)

    hipMemsetAsync(ip, 0, (size_t)(16 + 2 * N) * sizeof(int), stream);

    sniff_kernel<<<3, 256, 0, stream>>>(x, W1, ei, E, flags);
    count_kernel<<<(E + 255) / 256, 256, 0, stream>>>(ei, E, flags, counts);
    dinv_kernel<<<(N + 255) / 256, 256, 0, stream>>>(counts, dinv, N);
    scan_kernel<<<1, 256, 0, stream>>>(counts, rowptr, N);
    fill_kernel<<<(E + 255) / 256, 256, 0, stream>>>(ei, E, flags, rowptr, cursor, csr_src);
    repack_kernel<<<3, 256, 0, stream>>>(W1, W2, Wl, flags, Bp1, Bp2, Bp3);

    gemm1_mfma_kernel<<<(N + 127) / 128, 256, 0, stream>>>((const short*)x, Bp1, flags, h1x, N);
    gemm1_fallback_kernel<<<(N + 3) / 4, 256, 0, stream>>>(x, W1, flags, h1x, N);
    gather1_kernel<<<(N + 3) / 4, 256, 0, stream>>>(h1x, dinv, rowptr, csr_src, b1, flags, h1, h1b, N);

    // bf16-x path
    gemm2_mfma_kernel<<<(N + 63) / 64, 256, 0, stream>>>((const short*)h1b, Bp2, flags, h2x, N);
    gather2_kernel<<<(N + 7) / 8, 256, 0, stream>>>(h2x, dinv, rowptr, csr_src, b2, flags, h2b, N);
    final_mfma_kernel<<<(N + 63) / 64, 256, 0, stream>>>((const short*)x, (const short*)h1b,
                                                         (const short*)h2b, Bp3, bl, flags,
                                                         (bf16*)d_out, N);
    // fp32-x fallback path
    gemm2_kernel<<<(N + 7) / 8, 256, 0, stream>>>(h1, W2, flags, h2x, N);
    final_kernel<<<(N + 7) / 8, 256, 0, stream>>>(x, h1, h2x, dinv, rowptr, csr_src, b2, Wl, bl, flags, d_out, N);
}

// Round 9
// 643.694 us; speedup vs baseline: 1.5863x; 1.5863x over previous
//
#include <hip/hip_runtime.h>
#include <hip/hip_bf16.h>

typedef __hip_bfloat16 bf16;
typedef __attribute__((ext_vector_type(8))) short short8;   // 8 bf16 (4 VGPRs)
typedef __attribute__((ext_vector_type(4))) float f32x4;    // MFMA accumulator

#define MFMA16(a, b, c) __builtin_amdgcn_mfma_f32_16x16x32_bf16((a), (b), (c), 0, 0, 0)

// dual-mode float load: f32 ? float buffer : bf16 buffer (same element index)
static __device__ __forceinline__ float ldf(const void* p, long long i, bool f32) {
    return f32 ? ((const float*)p)[i] : __bfloat162float(((const bf16*)p)[i]);
}

static __device__ __forceinline__ short f2bs(float v) {
    union { bf16 h; short s; } u; u.h = __float2bfloat16(v); return u.s;
}

// ---------------------------------------------------------------- encoding sniffer
// flags[0]: x is fp32?  flags[1]: weights are fp32?  flags[2]: edge_index is int64?
// MEASURED (R1 NaN-fail + R8 gating probe): this harness delivers x=fp32, W=fp32, out=fp32.
__global__ __launch_bounds__(256, 4)
void sniff_kernel(const void* __restrict__ x, const void* __restrict__ w,
                  const int* __restrict__ ei, int E, int* __restrict__ flags) {
    __shared__ int cnt;
    if (threadIdx.x == 0) cnt = 0;
    __syncthreads();
    if (blockIdx.x < 2) {
        const unsigned short* u = (const unsigned short*)(blockIdx.x == 0 ? x : w);
        int bad = 0;
        for (int i = threadIdx.x; i < 4096; i += 256) {
            unsigned e = (u[i] >> 7) & 0xFF;
            if (e >= 0xA0) bad++;
        }
        atomicAdd(&cnt, bad);
        __syncthreads();
        if (threadIdx.x == 0) flags[blockIdx.x] = (cnt > 16) ? 1 : 0;
    } else {
        int nz = 0;
        for (int i = threadIdx.x; i < 1024; i += 256)
            if (ei[2 * i + 1] != 0) nz++;
        atomicAdd(&cnt, nz);
        __syncthreads();
        if (threadIdx.x == 0) flags[2] = (cnt == 0) ? 1 : 0;
    }
}

static __device__ __forceinline__ int ld_src(const int* ei, int E, int e, bool i64) {
    return i64 ? ei[2 * e] : ei[e];
}
static __device__ __forceinline__ int ld_dst(const int* ei, int E, int e, bool i64) {
    return i64 ? ei[2 * (E + e)] : ei[E + e];
}

// ---------------------------------------------------------------- degree counts (int)
__global__ __launch_bounds__(256, 4)
void count_kernel(const int* __restrict__ ei, int E, const int* __restrict__ flags,
                  int* __restrict__ counts) {
    int i = blockIdx.x * blockDim.x + threadIdx.x;
    if (i >= E) return;
    bool i64 = flags[2] != 0;
    atomicAdd(&counts[ld_dst(ei, E, i, i64)], 1);
}

__global__ __launch_bounds__(256, 4)
void dinv_kernel(const int* __restrict__ counts, float* __restrict__ dinv, int N) {
    int i = blockIdx.x * blockDim.x + threadIdx.x;
    if (i < N) dinv[i] = rsqrtf((float)counts[i] + 1.0f);
}

// ---------------------------------------------------------------- exclusive scan (single block)
__global__ __launch_bounds__(256, 4)
void scan_kernel(const int* __restrict__ counts, int* __restrict__ rowptr, int N) {
    __shared__ int bs[256];
    const int T = 256;
    int chunk = (N + T - 1) / T;
    int lo = threadIdx.x * chunk;
    int hi = lo + chunk; if (hi > N) hi = N; if (lo > N) lo = N;
    int sum = 0;
    for (int i = lo; i < hi; i++) sum += counts[i];
    bs[threadIdx.x] = sum;
    __syncthreads();
    for (int off = 1; off < T; off <<= 1) {
        int t = 0;
        if ((int)threadIdx.x >= off) t = bs[threadIdx.x - off];
        __syncthreads();
        if ((int)threadIdx.x >= off) bs[threadIdx.x] += t;
        __syncthreads();
    }
    int run = bs[threadIdx.x] - sum;
    for (int i = lo; i < hi; i++) { rowptr[i] = run; run += counts[i]; }
    if (hi == N && lo < N) rowptr[N] = run;
    if (N == 0 && threadIdx.x == 0) rowptr[0] = 0;
}

// ---------------------------------------------------------------- CSR fill (counting sort by dst)
__global__ __launch_bounds__(256, 4)
void fill_kernel(const int* __restrict__ ei, int E, const int* __restrict__ flags,
                 const int* __restrict__ rowptr, int* __restrict__ cursor,
                 int* __restrict__ csr_src) {
    int e = blockIdx.x * blockDim.x + threadIdx.x;
    if (e >= E) return;
    bool i64 = flags[2] != 0;
    int s = ld_src(ei, E, e, i64), d = ld_dst(ei, E, e, i64);
    int p = atomicAdd(&cursor[d], 1);
    csr_src[rowptr[d] + p] = s;
}

// ---------------------------------------------------------------- weight -> MFMA B-fragment packs
// frag f = kstep*ntiles + ntile; slot s = f*64 + lane; element j (0..7):
//   W[kstep*32 + (lane>>4)*8 + j][ntile*16 + (lane&15)]  (fw-aware fp32/bf16 read)
__global__ __launch_bounds__(256, 4)
void repack_kernel(const void* __restrict__ W1, const void* __restrict__ W2,
                   const void* __restrict__ Wl, const int* __restrict__ flags,
                   bf16* __restrict__ Bp1, bf16* __restrict__ Bp2, bf16* __restrict__ Bp3) {
    bool fw = flags[1] != 0;
    const void* W; bf16* Bp; int ntiles, nc, nfrag;
    if (blockIdx.x == 0)      { W = W1; Bp = Bp1; ntiles = 4; nc = 64; nfrag = 16; }
    else if (blockIdx.x == 1) { W = W2; Bp = Bp2; ntiles = 2; nc = 32; nfrag = 4;  }
    else                      { W = Wl; Bp = Bp3; ntiles = 2; nc = 32; nfrag = 14; }
    for (int s = threadIdx.x; s < nfrag * 64; s += 256) {
        int f = s >> 6, lane = s & 63;
        int kstep = f / ntiles, ntile = f % ntiles;
        int n = ntile * 16 + (lane & 15);
        int kbase = kstep * 32 + (lane >> 4) * 8;
#pragma unroll
        for (int j = 0; j < 8; j++)
            Bp[s * 8 + j] = __float2bfloat16(ldf(W, (long long)(kbase + j) * nc + n, fw));
    }
}

// ---------------------------------------------------------------- x -> xb (bf16), both source dtypes
__global__ __launch_bounds__(256, 4)
void cvt_x_kernel(const void* __restrict__ x, const int* __restrict__ flags,
                  short* __restrict__ xb, long long total8) {
    long long i = (long long)blockIdx.x * 256 + threadIdx.x;
    if (i >= total8) return;
    bool fx = flags[0] != 0;
    short8 o;
    if (fx) {
        const float4* xf = (const float4*)x;
        float4 a = xf[i * 2], b = xf[i * 2 + 1];
        o[0] = f2bs(a.x); o[1] = f2bs(a.y); o[2] = f2bs(a.z); o[3] = f2bs(a.w);
        o[4] = f2bs(b.x); o[5] = f2bs(b.y); o[6] = f2bs(b.z); o[7] = f2bs(b.w);
    } else {
        o = ((const short8*)x)[i];
    }
    ((short8*)xb)[i] = o;
}

// ---------------------------------------------------------------- GEMM1 (MFMA): xb[N,128]@W1 -> h1x[N,32]... [N,64] f32
__global__ __launch_bounds__(256, 3)
void gemm1_mfma_kernel(const short* __restrict__ xb, const bf16* __restrict__ Bpack,
                       float* __restrict__ h1x, int N) {
    int lane = threadIdx.x & 63, wave = threadIdx.x >> 6;
    int m = lane & 15, quad = lane >> 4;
    int base = blockIdx.x * 128 + wave * 32;
    if (base >= N) return;
    const short8* bp = (const short8*)Bpack;
    short8 B[16];
#pragma unroll
    for (int i = 0; i < 16; i++) B[i] = bp[i * 64 + lane];
    if (base + 32 <= N) {
#pragma unroll
        for (int t = 0; t < 2; t++) {
            int r0 = base + t * 16;
            const short* xr = &xb[(long long)(r0 + m) * 128 + quad * 8];
            short8 A[4];
#pragma unroll
            for (int k = 0; k < 4; k++) A[k] = *(const short8*)(xr + k * 32);
            f32x4 acc[4];
#pragma unroll
            for (int nt = 0; nt < 4; nt++) acc[nt] = (f32x4){0.f, 0.f, 0.f, 0.f};
#pragma unroll
            for (int k = 0; k < 4; k++) {
#pragma unroll
                for (int nt = 0; nt < 4; nt++) acc[nt] = MFMA16(A[k], B[k * 4 + nt], acc[nt]);
            }
            // C/D: col = lane&15, row = quad*4 + r  [m89/m91]
            float* o = &h1x[(long long)(r0 + quad * 4) * 64 + m];
#pragma unroll
            for (int nt = 0; nt < 4; nt++) {
#pragma unroll
                for (int r = 0; r < 4; r++) o[(long long)r * 64 + nt * 16] = acc[nt][r];
            }
        }
    } else {
#pragma unroll
        for (int t = 0; t < 2; t++) {
            int r0 = base + t * 16;
            int row = r0 + m;
            short8 A[4];
#pragma unroll
            for (int k = 0; k < 4; k++) A[k] = (short8){0,0,0,0,0,0,0,0};
            if (row < N) {
                const short* xr = &xb[(long long)row * 128 + quad * 8];
#pragma unroll
                for (int k = 0; k < 4; k++) A[k] = *(const short8*)(xr + k * 32);
            }
            f32x4 acc[4];
#pragma unroll
            for (int nt = 0; nt < 4; nt++) acc[nt] = (f32x4){0.f, 0.f, 0.f, 0.f};
#pragma unroll
            for (int k = 0; k < 4; k++) {
#pragma unroll
                for (int nt = 0; nt < 4; nt++) acc[nt] = MFMA16(A[k], B[k * 4 + nt], acc[nt]);
            }
#pragma unroll
            for (int r = 0; r < 4; r++) {
                int orow = r0 + quad * 4 + r;
                if (orow < N) {
                    float* o = &h1x[(long long)orow * 64 + m];
#pragma unroll
                    for (int nt = 0; nt < 4; nt++) o[nt * 16] = acc[nt][r];
                }
            }
        }
    }
}

// ---------------------------------------------------------------- gather layer 1: one wave per node -> h1b (bf16)
__global__ __launch_bounds__(256, 4)
void gather1_kernel(const float* __restrict__ h1x, const float* __restrict__ dinv,
                    const int* __restrict__ rowptr, const int* __restrict__ csr_src,
                    const void* __restrict__ b1, const int* __restrict__ flags,
                    bf16* __restrict__ h1b, int N) {
    bool fw = flags[1] != 0;
    int lane = threadIdx.x & 63;
    int node = blockIdx.x * 4 + (threadIdx.x >> 6);
    if (node >= N) return;
    int beg = rowptr[node], end = rowptr[node + 1];
    float dvd = dinv[node];
    float acc = 0.f;
    for (int b = beg; b < end; b += 64) {
        int cnt = end - b; if (cnt > 64) cnt = 64;
        int s = 0; float dvs = 0.f;
        if (lane < cnt) { s = csr_src[b + lane]; dvs = dinv[s]; }
        for (int j = 0; j < cnt; j++) {
            int sj = __shfl(s, j);
            float nm = __shfl(dvs, j) * dvd;
            acc = fmaf(h1x[(long long)sj * 64 + lane], nm, acc);
        }
    }
    float v = acc + h1x[(long long)node * 64 + lane] * (dvd * dvd) + ldf(b1, lane, fw);
    h1b[(long long)node * 64 + lane] = __float2bfloat16(fmaxf(v, 0.f));
}

// ---------------------------------------------------------------- GEMM2 (MFMA): h1b[N,64]@W2 -> h2x[N,32] f32
__global__ __launch_bounds__(256, 4)
void gemm2_mfma_kernel(const short* __restrict__ h1b, const bf16* __restrict__ Bpack,
                       float* __restrict__ h2x, int N) {
    int lane = threadIdx.x & 63, wave = threadIdx.x >> 6;
    int m = lane & 15, quad = lane >> 4;
    int r0 = blockIdx.x * 64 + wave * 16;
    if (r0 >= N) return;
    const short8* bp = (const short8*)Bpack;
    short8 B[4];
#pragma unroll
    for (int i = 0; i < 4; i++) B[i] = bp[i * 64 + lane];
    f32x4 acc0 = {0.f,0.f,0.f,0.f}, acc1 = {0.f,0.f,0.f,0.f};
    if (r0 + 16 <= N) {
        const short* xr = &h1b[(long long)(r0 + m) * 64 + quad * 8];
#pragma unroll
        for (int k = 0; k < 2; k++) {
            short8 A = *(const short8*)(xr + k * 32);
            acc0 = MFMA16(A, B[k * 2 + 0], acc0);
            acc1 = MFMA16(A, B[k * 2 + 1], acc1);
        }
        float* o = &h2x[(long long)(r0 + quad * 4) * 32 + m];
#pragma unroll
        for (int r = 0; r < 4; r++) { o[(long long)r * 32] = acc0[r]; o[(long long)r * 32 + 16] = acc1[r]; }
    } else {
        int row = r0 + m;
#pragma unroll
        for (int k = 0; k < 2; k++) {
            short8 A = {0,0,0,0,0,0,0,0};
            if (row < N) A = *(const short8*)&h1b[(long long)row * 64 + k * 32 + quad * 8];
            acc0 = MFMA16(A, B[k * 2 + 0], acc0);
            acc1 = MFMA16(A, B[k * 2 + 1], acc1);
        }
#pragma unroll
        for (int r = 0; r < 4; r++) {
            int orow = r0 + quad * 4 + r;
            if (orow < N) {
                h2x[(long long)orow * 32 + m] = acc0[r];
                h2x[(long long)orow * 32 + 16 + m] = acc1[r];
            }
        }
    }
}

// ---------------------------------------------------------------- gather layer 2: h2x -> h2b (bf16)
__global__ __launch_bounds__(256, 4)
void gather2_kernel(const float* __restrict__ h2x, const float* __restrict__ dinv,
                    const int* __restrict__ rowptr, const int* __restrict__ csr_src,
                    const void* __restrict__ b2, const int* __restrict__ flags,
                    bf16* __restrict__ h2b, int N) {
    bool fw = flags[1] != 0;
    int j = threadIdx.x & 31;
    int node = blockIdx.x * 8 + (threadIdx.x >> 5);
    if (node >= N) return;
    int beg = rowptr[node], end = rowptr[node + 1];
    float dvd = dinv[node];
    float acc = 0.f;
    for (int b = beg; b < end; b += 32) {
        int cnt = end - b; if (cnt > 32) cnt = 32;
        int s = 0; float dvs = 0.f;
        if (j < cnt) { s = csr_src[b + j]; dvs = dinv[s]; }
        for (int jj = 0; jj < cnt; jj++) {
            int sj = __shfl(s, jj, 32);
            float nm = __shfl(dvs, jj, 32) * dvd;
            acc = fmaf(h2x[(long long)sj * 32 + j], nm, acc);
        }
    }
    acc += h2x[(long long)node * 32 + j] * (dvd * dvd) + ldf(b2, j, fw);
    h2b[(long long)node * 32 + j] = __float2bfloat16(acc);
}

// ---------------------------------------------------------------- final (MFMA): [xb|h1b|h2b]@Wl + bl -> log_softmax
__global__ __launch_bounds__(256, 2)
void final_mfma_kernel(const short* __restrict__ xb, const short* __restrict__ h1b,
                       const short* __restrict__ h2b, const bf16* __restrict__ Bpack,
                       const void* __restrict__ bl, const int* __restrict__ flags,
                       void* __restrict__ out, int N) {
    bool fw = flags[1] != 0, fx = flags[0] != 0;
    int lane = threadIdx.x & 63, wave = threadIdx.x >> 6;
    int m = lane & 15, quad = lane >> 4;
    int r0 = blockIdx.x * 64 + wave * 16;
    if (r0 >= N) return;
    const short8* bp = (const short8*)Bpack;
    short8 B[14];
#pragma unroll
    for (int i = 0; i < 14; i++) B[i] = bp[i * 64 + lane];
    f32x4 acc0 = {0.f,0.f,0.f,0.f}, acc1 = {0.f,0.f,0.f,0.f};
    bool full = (r0 + 16 <= N);
    int row = r0 + m;
    bool rowok = full || (row < N);
#pragma unroll
    for (int s = 0; s < 7; s++) {
        short8 A = {0,0,0,0,0,0,0,0};
        if (rowok) {
            const short* p;
            if (s < 4)      p = &xb [(long long)row * 128 + s * 32 + quad * 8];
            else if (s < 6) p = &h1b[(long long)row * 64 + (s - 4) * 32 + quad * 8];
            else            p = &h2b[(long long)row * 32 + quad * 8];
            A = *(const short8*)p;
        }
        acc0 = MFMA16(A, B[s * 2 + 0], acc0);
        acc1 = MFMA16(A, B[s * 2 + 1], acc1);
    }
    float bl0 = ldf(bl, m, fw), bl1 = ldf(bl, m + 16, fw);
#pragma unroll
    for (int r = 0; r < 4; r++) {
        float v0 = acc0[r] + bl0, v1 = acc1[r] + bl1;
        float mx = fmaxf(v0, v1);
#pragma unroll
        for (int o = 8; o > 0; o >>= 1) mx = fmaxf(mx, __shfl_xor(mx, o));
        float sm = __expf(v0 - mx) + __expf(v1 - mx);
#pragma unroll
        for (int o = 8; o > 0; o >>= 1) sm += __shfl_xor(sm, o);
        float lse = mx + __logf(sm);
        int orow = r0 + quad * 4 + r;
        if (orow < N) {
            if (fx) {
                ((float*)out)[(long long)orow * 32 + m]      = v0 - lse;
                ((float*)out)[(long long)orow * 32 + 16 + m] = v1 - lse;
            } else {
                ((bf16*)out)[(long long)orow * 32 + m]      = __float2bfloat16(v0 - lse);
                ((bf16*)out)[(long long)orow * 32 + 16 + m] = __float2bfloat16(v1 - lse);
            }
        }
    }
}

extern "C" void kernel_launch(void* const* d_in, const int* in_sizes, int n_in,
                              void* d_out, int out_size, void* d_ws, size_t ws_size,
                              hipStream_t stream) {
    const void* x  = d_in[0];
    const int*  ei = (const int*)d_in[1];
    const void* W1 = d_in[2];
    const void* b1 = d_in[3];
    const void* W2 = d_in[4];
    const void* b2 = d_in[5];
    const void* Wl = d_in[6];
    const void* bl = d_in[7];

    int N = in_sizes[0] / 128;
    int E = in_sizes[1] / 2;

    // ws layout (4B units), ~72 MB at N=100k,E=1.6M:
    // [flags 16 | counts N | cursor N | dinv N | rowptr N+16 | Bp1 4096 | Bp2 1024 | Bp3 3584 |
    //  csr_src E | xb N*64 | A N*64 (h1x f32; later h2x f32 in [0,N*32), h2b bf16 in [N*48,N*64)) |
    //  h1b N*32]
    int* ip      = (int*)d_ws;
    int* flags   = ip;
    int* counts  = ip + 16;
    int* cursor  = counts + N;
    float* dinv  = (float*)(cursor + N);
    int* rowptr  = (int*)(dinv + N);
    bf16* Bp1    = (bf16*)(rowptr + N + 16);
    bf16* Bp2    = (bf16*)((int*)Bp1 + 4096);
    bf16* Bp3    = (bf16*)((int*)Bp2 + 1024);
    int* csr_src = (int*)Bp3 + 3584;
    short* xb    = (short*)(csr_src + E);                 // N*64 ints
    int*   Ai    = (int*)xb + (size_t)N * 64;             // region A: N*64 ints
    float* h1x   = (float*)Ai;
    float* h2x   = (float*)Ai;                            // alias (h1x dead after gather1)
    bf16*  h2b   = (bf16*)(Ai + (size_t)N * 48);          // upper quarter of A
    bf16*  h1b   = (bf16*)(Ai + (size_t)N * 64);          // N*32 ints

    hipMemsetAsync(ip, 0, (size_t)(16 + 2 * N) * sizeof(int), stream);

    sniff_kernel<<<3, 256, 0, stream>>>(x, W1, ei, E, flags);
    count_kernel<<<(E + 255) / 256, 256, 0, stream>>>(ei, E, flags, counts);
    dinv_kernel<<<(N + 255) / 256, 256, 0, stream>>>(counts, dinv, N);
    scan_kernel<<<1, 256, 0, stream>>>(counts, rowptr, N);
    fill_kernel<<<(E + 255) / 256, 256, 0, stream>>>(ei, E, flags, rowptr, cursor, csr_src);
    repack_kernel<<<3, 256, 0, stream>>>(W1, W2, Wl, flags, Bp1, Bp2, Bp3);

    long long total8 = (long long)N * 16;   // groups of 8 elements of x
    cvt_x_kernel<<<(int)((total8 + 255) / 256), 256, 0, stream>>>(x, flags, xb, total8);

    gemm1_mfma_kernel<<<(N + 127) / 128, 256, 0, stream>>>(xb, Bp1, h1x, N);
    gather1_kernel<<<(N + 3) / 4, 256, 0, stream>>>(h1x, dinv, rowptr, csr_src, b1, flags, h1b, N);
    gemm2_mfma_kernel<<<(N + 63) / 64, 256, 0, stream>>>((const short*)h1b, Bp2, h2x, N);
    gather2_kernel<<<(N + 7) / 8, 256, 0, stream>>>(h2x, dinv, rowptr, csr_src, b2, flags, h2b, N);
    final_mfma_kernel<<<(N + 63) / 64, 256, 0, stream>>>(xb, (const short*)h1b, (const short*)h2b,
                                                         Bp3, bl, flags, d_out, N);
}

// Round 10
// 509.305 us; speedup vs baseline: 2.0049x; 1.2639x over previous
//
#include <hip/hip_runtime.h>
#include <hip/hip_bf16.h>

typedef __hip_bfloat16 bf16;
typedef __attribute__((ext_vector_type(8))) short short8;   // 8 bf16 (4 VGPRs)
typedef __attribute__((ext_vector_type(4))) float f32x4;    // MFMA accumulator

#define MFMA16(a, b, c) __builtin_amdgcn_mfma_f32_16x16x32_bf16((a), (b), (c), 0, 0, 0)

// dual-mode float load: f32 ? float buffer : bf16 buffer (same element index)
static __device__ __forceinline__ float ldf(const void* p, long long i, bool f32) {
    return f32 ? ((const float*)p)[i] : __bfloat162float(((const bf16*)p)[i]);
}

static __device__ __forceinline__ short f2bs(float v) {
    union { bf16 h; short s; } u; u.h = __float2bfloat16(v); return u.s;
}

// ---------------------------------------------------------------- encoding sniffer
// flags[0]: x is fp32?  flags[1]: weights are fp32?  flags[2]: edge_index is int64?
// MEASURED (R1 NaN-fail + R8 gating probe): this harness delivers x=fp32, W=fp32, out=fp32.
__global__ __launch_bounds__(256, 4)
void sniff_kernel(const void* __restrict__ x, const void* __restrict__ w,
                  const int* __restrict__ ei, int E, int* __restrict__ flags) {
    __shared__ int cnt;
    if (threadIdx.x == 0) cnt = 0;
    __syncthreads();
    if (blockIdx.x < 2) {
        const unsigned short* u = (const unsigned short*)(blockIdx.x == 0 ? x : w);
        int bad = 0;
        for (int i = threadIdx.x; i < 4096; i += 256) {
            unsigned e = (u[i] >> 7) & 0xFF;
            if (e >= 0xA0) bad++;
        }
        atomicAdd(&cnt, bad);
        __syncthreads();
        if (threadIdx.x == 0) flags[blockIdx.x] = (cnt > 16) ? 1 : 0;
    } else {
        int nz = 0;
        for (int i = threadIdx.x; i < 1024; i += 256)
            if (ei[2 * i + 1] != 0) nz++;
        atomicAdd(&cnt, nz);
        __syncthreads();
        if (threadIdx.x == 0) flags[2] = (cnt == 0) ? 1 : 0;
    }
}

static __device__ __forceinline__ int ld_src(const int* ei, int E, int e, bool i64) {
    return i64 ? ei[2 * e] : ei[e];
}
static __device__ __forceinline__ int ld_dst(const int* ei, int E, int e, bool i64) {
    return i64 ? ei[2 * (E + e)] : ei[E + e];
}

// ---------------------------------------------------------------- degree counts (int)
__global__ __launch_bounds__(256, 4)
void count_kernel(const int* __restrict__ ei, int E, const int* __restrict__ flags,
                  int* __restrict__ counts) {
    int i = blockIdx.x * blockDim.x + threadIdx.x;
    if (i >= E) return;
    bool i64 = flags[2] != 0;
    atomicAdd(&counts[ld_dst(ei, E, i, i64)], 1);
}

__global__ __launch_bounds__(256, 4)
void dinv_kernel(const int* __restrict__ counts, float* __restrict__ dinv, int N) {
    int i = blockIdx.x * blockDim.x + threadIdx.x;
    if (i < N) dinv[i] = rsqrtf((float)counts[i] + 1.0f);
}

// ---------------------------------------------------------------- 3-phase multi-block exclusive scan
// phase 1: block b sums counts[b*2048 .. b*2048+2047] -> blocksums[b]
__global__ __launch_bounds__(256, 4)
void scan1_kernel(const int* __restrict__ counts, int* __restrict__ blocksums, int N) {
    __shared__ int bs[256];
    int base = blockIdx.x * 2048 + threadIdx.x * 8;
    int s = 0;
#pragma unroll
    for (int i = 0; i < 8; i++) { int idx = base + i; if (idx < N) s += counts[idx]; }
    bs[threadIdx.x] = s;
    __syncthreads();
    for (int off = 128; off > 0; off >>= 1) {
        if ((int)threadIdx.x < off) bs[threadIdx.x] += bs[threadIdx.x + off];
        __syncthreads();
    }
    if (threadIdx.x == 0) blocksums[blockIdx.x] = bs[0];
}

// phase 2: single block, exclusive scan of nb blocksums (nb ~ 49); also rowptr[N] = E
__global__ __launch_bounds__(256, 4)
void scan2_kernel(int* __restrict__ blocksums, int nb, int* __restrict__ rowptr, int N, int E) {
    __shared__ int bs[256];
    int chunk = (nb + 255) / 256;
    int lo = threadIdx.x * chunk, hi = lo + chunk;
    if (hi > nb) hi = nb; if (lo > nb) lo = nb;
    int sum = 0;
    for (int i = lo; i < hi; i++) sum += blocksums[i];
    bs[threadIdx.x] = sum;
    __syncthreads();
    int v = sum;
    for (int off = 1; off < 256; off <<= 1) {
        int t = ((int)threadIdx.x >= off) ? bs[threadIdx.x - off] : 0;
        __syncthreads();
        bs[threadIdx.x] += t;
        __syncthreads();
    }
    int run = bs[threadIdx.x] - v;   // exclusive base for this thread's chunk
    for (int i = lo; i < hi; i++) { int c = blocksums[i]; blocksums[i] = run; run += c; }
    if (threadIdx.x == 0) rowptr[N] = E;
}

// phase 3: block b writes exclusive prefix for its 2048-elem chunk
__global__ __launch_bounds__(256, 4)
void scan3_kernel(const int* __restrict__ counts, const int* __restrict__ blocksums,
                  int* __restrict__ rowptr, int N) {
    __shared__ int bs[256];
    int base = blockIdx.x * 2048 + threadIdx.x * 8;
    int local[8];
    int s = 0;
#pragma unroll
    for (int i = 0; i < 8; i++) {
        int idx = base + i;
        int c = (idx < N) ? counts[idx] : 0;
        local[i] = s; s += c;
    }
    bs[threadIdx.x] = s;
    __syncthreads();
    int v = s;
    for (int off = 1; off < 256; off <<= 1) {
        int t = ((int)threadIdx.x >= off) ? bs[threadIdx.x - off] : 0;
        __syncthreads();
        bs[threadIdx.x] += t;
        __syncthreads();
    }
    int excl = bs[threadIdx.x] - v;
    int offset = blocksums[blockIdx.x] + excl;
#pragma unroll
    for (int i = 0; i < 8; i++) {
        int idx = base + i;
        if (idx < N) rowptr[idx] = offset + local[i];
    }
}

// ---------------------------------------------------------------- CSR fill (counting sort by dst)
__global__ __launch_bounds__(256, 4)
void fill_kernel(const int* __restrict__ ei, int E, const int* __restrict__ flags,
                 const int* __restrict__ rowptr, int* __restrict__ cursor,
                 int* __restrict__ csr_src) {
    int e = blockIdx.x * blockDim.x + threadIdx.x;
    if (e >= E) return;
    bool i64 = flags[2] != 0;
    int s = ld_src(ei, E, e, i64), d = ld_dst(ei, E, e, i64);
    int p = atomicAdd(&cursor[d], 1);
    csr_src[rowptr[d] + p] = s;
}

// ---------------------------------------------------------------- weight -> MFMA B-fragment packs
// frag f = kstep*ntiles + ntile; slot s = f*64 + lane; element j (0..7):
//   W[kstep*32 + (lane>>4)*8 + j][ntile*16 + (lane&15)]  (fw-aware fp32/bf16 read)
__global__ __launch_bounds__(256, 4)
void repack_kernel(const void* __restrict__ W1, const void* __restrict__ W2,
                   const void* __restrict__ Wl, const int* __restrict__ flags,
                   bf16* __restrict__ Bp1, bf16* __restrict__ Bp2, bf16* __restrict__ Bp3) {
    bool fw = flags[1] != 0;
    const void* W; bf16* Bp; int ntiles, nc, nfrag;
    if (blockIdx.x == 0)      { W = W1; Bp = Bp1; ntiles = 4; nc = 64; nfrag = 16; }
    else if (blockIdx.x == 1) { W = W2; Bp = Bp2; ntiles = 2; nc = 32; nfrag = 4;  }
    else                      { W = Wl; Bp = Bp3; ntiles = 2; nc = 32; nfrag = 14; }
    for (int s = threadIdx.x; s < nfrag * 64; s += 256) {
        int f = s >> 6, lane = s & 63;
        int kstep = f / ntiles, ntile = f % ntiles;
        int n = ntile * 16 + (lane & 15);
        int kbase = kstep * 32 + (lane >> 4) * 8;
#pragma unroll
        for (int j = 0; j < 8; j++)
            Bp[s * 8 + j] = __float2bfloat16(ldf(W, (long long)(kbase + j) * nc + n, fw));
    }
}

// ---------------------------------------------------------------- x -> xb (bf16), both source dtypes
__global__ __launch_bounds__(256, 4)
void cvt_x_kernel(const void* __restrict__ x, const int* __restrict__ flags,
                  short* __restrict__ xb, long long total8) {
    long long i = (long long)blockIdx.x * 256 + threadIdx.x;
    if (i >= total8) return;
    bool fx = flags[0] != 0;
    short8 o;
    if (fx) {
        const float4* xf = (const float4*)x;
        float4 a = xf[i * 2], b = xf[i * 2 + 1];
        o[0] = f2bs(a.x); o[1] = f2bs(a.y); o[2] = f2bs(a.z); o[3] = f2bs(a.w);
        o[4] = f2bs(b.x); o[5] = f2bs(b.y); o[6] = f2bs(b.z); o[7] = f2bs(b.w);
    } else {
        o = ((const short8*)x)[i];
    }
    ((short8*)xb)[i] = o;
}

// ---------------------------------------------------------------- GEMM1 (MFMA): xb[N,128]@W1 -> h1x[N,64] f32
__global__ __launch_bounds__(256, 3)
void gemm1_mfma_kernel(const short* __restrict__ xb, const bf16* __restrict__ Bpack,
                       float* __restrict__ h1x, int N) {
    int lane = threadIdx.x & 63, wave = threadIdx.x >> 6;
    int m = lane & 15, quad = lane >> 4;
    int base = blockIdx.x * 128 + wave * 32;
    if (base >= N) return;
    const short8* bp = (const short8*)Bpack;
    short8 B[16];
#pragma unroll
    for (int i = 0; i < 16; i++) B[i] = bp[i * 64 + lane];
    if (base + 32 <= N) {
#pragma unroll
        for (int t = 0; t < 2; t++) {
            int r0 = base + t * 16;
            const short* xr = &xb[(long long)(r0 + m) * 128 + quad * 8];
            short8 A[4];
#pragma unroll
            for (int k = 0; k < 4; k++) A[k] = *(const short8*)(xr + k * 32);
            f32x4 acc[4];
#pragma unroll
            for (int nt = 0; nt < 4; nt++) acc[nt] = (f32x4){0.f, 0.f, 0.f, 0.f};
#pragma unroll
            for (int k = 0; k < 4; k++) {
#pragma unroll
                for (int nt = 0; nt < 4; nt++) acc[nt] = MFMA16(A[k], B[k * 4 + nt], acc[nt]);
            }
            // C/D: col = lane&15, row = quad*4 + r  [m89/m91]
            float* o = &h1x[(long long)(r0 + quad * 4) * 64 + m];
#pragma unroll
            for (int nt = 0; nt < 4; nt++) {
#pragma unroll
                for (int r = 0; r < 4; r++) o[(long long)r * 64 + nt * 16] = acc[nt][r];
            }
        }
    } else {
#pragma unroll
        for (int t = 0; t < 2; t++) {
            int r0 = base + t * 16;
            int row = r0 + m;
            short8 A[4];
#pragma unroll
            for (int k = 0; k < 4; k++) A[k] = (short8){0,0,0,0,0,0,0,0};
            if (row < N) {
                const short* xr = &xb[(long long)row * 128 + quad * 8];
#pragma unroll
                for (int k = 0; k < 4; k++) A[k] = *(const short8*)(xr + k * 32);
            }
            f32x4 acc[4];
#pragma unroll
            for (int nt = 0; nt < 4; nt++) acc[nt] = (f32x4){0.f, 0.f, 0.f, 0.f};
#pragma unroll
            for (int k = 0; k < 4; k++) {
#pragma unroll
                for (int nt = 0; nt < 4; nt++) acc[nt] = MFMA16(A[k], B[k * 4 + nt], acc[nt]);
            }
#pragma unroll
            for (int r = 0; r < 4; r++) {
                int orow = r0 + quad * 4 + r;
                if (orow < N) {
                    float* o = &h1x[(long long)orow * 64 + m];
#pragma unroll
                    for (int nt = 0; nt < 4; nt++) o[nt * 16] = acc[nt][r];
                }
            }
        }
    }
}

// ---------------------------------------------------------------- gather layer 1: one wave per node -> h1b (bf16)
__global__ __launch_bounds__(256, 4)
void gather1_kernel(const float* __restrict__ h1x, const float* __restrict__ dinv,
                    const int* __restrict__ rowptr, const int* __restrict__ csr_src,
                    const void* __restrict__ b1, const int* __restrict__ flags,
                    bf16* __restrict__ h1b, int N) {
    bool fw = flags[1] != 0;
    int lane = threadIdx.x & 63;
    int node = blockIdx.x * 4 + (threadIdx.x >> 6);
    if (node >= N) return;
    int beg = rowptr[node], end = rowptr[node + 1];
    float dvd = dinv[node];
    float acc = 0.f;
    for (int b = beg; b < end; b += 64) {
        int cnt = end - b; if (cnt > 64) cnt = 64;
        int s = 0; float dvs = 0.f;
        if (lane < cnt) { s = csr_src[b + lane]; dvs = dinv[s]; }
        for (int j = 0; j < cnt; j++) {
            int sj = __shfl(s, j);
            float nm = __shfl(dvs, j) * dvd;
            acc = fmaf(h1x[(long long)sj * 64 + lane], nm, acc);
        }
    }
    float v = acc + h1x[(long long)node * 64 + lane] * (dvd * dvd) + ldf(b1, lane, fw);
    h1b[(long long)node * 64 + lane] = __float2bfloat16(fmaxf(v, 0.f));
}

// ---------------------------------------------------------------- GEMM2 (MFMA): h1b[N,64]@W2 -> h2x[N,32] f32
__global__ __launch_bounds__(256, 4)
void gemm2_mfma_kernel(const short* __restrict__ h1b, const bf16* __restrict__ Bpack,
                       float* __restrict__ h2x, int N) {
    int lane = threadIdx.x & 63, wave = threadIdx.x >> 6;
    int m = lane & 15, quad = lane >> 4;
    int r0 = blockIdx.x * 64 + wave * 16;
    if (r0 >= N) return;
    const short8* bp = (const short8*)Bpack;
    short8 B[4];
#pragma unroll
    for (int i = 0; i < 4; i++) B[i] = bp[i * 64 + lane];
    f32x4 acc0 = {0.f,0.f,0.f,0.f}, acc1 = {0.f,0.f,0.f,0.f};
    if (r0 + 16 <= N) {
        const short* xr = &h1b[(long long)(r0 + m) * 64 + quad * 8];
#pragma unroll
        for (int k = 0; k < 2; k++) {
            short8 A = *(const short8*)(xr + k * 32);
            acc0 = MFMA16(A, B[k * 2 + 0], acc0);
            acc1 = MFMA16(A, B[k * 2 + 1], acc1);
        }
        float* o = &h2x[(long long)(r0 + quad * 4) * 32 + m];
#pragma unroll
        for (int r = 0; r < 4; r++) { o[(long long)r * 32] = acc0[r]; o[(long long)r * 32 + 16] = acc1[r]; }
    } else {
        int row = r0 + m;
#pragma unroll
        for (int k = 0; k < 2; k++) {
            short8 A = {0,0,0,0,0,0,0,0};
            if (row < N) A = *(const short8*)&h1b[(long long)row * 64 + k * 32 + quad * 8];
            acc0 = MFMA16(A, B[k * 2 + 0], acc0);
            acc1 = MFMA16(A, B[k * 2 + 1], acc1);
        }
#pragma unroll
        for (int r = 0; r < 4; r++) {
            int orow = r0 + quad * 4 + r;
            if (orow < N) {
                h2x[(long long)orow * 32 + m] = acc0[r];
                h2x[(long long)orow * 32 + 16 + m] = acc1[r];
            }
        }
    }
}

// ---------------------------------------------------------------- gather layer 2: h2x -> h2b (bf16)
__global__ __launch_bounds__(256, 4)
void gather2_kernel(const float* __restrict__ h2x, const float* __restrict__ dinv,
                    const int* __restrict__ rowptr, const int* __restrict__ csr_src,
                    const void* __restrict__ b2, const int* __restrict__ flags,
                    bf16* __restrict__ h2b, int N) {
    bool fw = flags[1] != 0;
    int j = threadIdx.x & 31;
    int node = blockIdx.x * 8 + (threadIdx.x >> 5);
    if (node >= N) return;
    int beg = rowptr[node], end = rowptr[node + 1];
    float dvd = dinv[node];
    float acc = 0.f;
    for (int b = beg; b < end; b += 32) {
        int cnt = end - b; if (cnt > 32) cnt = 32;
        int s = 0; float dvs = 0.f;
        if (j < cnt) { s = csr_src[b + j]; dvs = dinv[s]; }
        for (int jj = 0; jj < cnt; jj++) {
            int sj = __shfl(s, jj, 32);
            float nm = __shfl(dvs, jj, 32) * dvd;
            acc = fmaf(h2x[(long long)sj * 32 + j], nm, acc);
        }
    }
    acc += h2x[(long long)node * 32 + j] * (dvd * dvd) + ldf(b2, j, fw);
    h2b[(long long)node * 32 + j] = __float2bfloat16(acc);
}

// ---------------------------------------------------------------- final (MFMA): [xb|h1b|h2b]@Wl + bl -> log_softmax
__global__ __launch_bounds__(256, 2)
void final_mfma_kernel(const short* __restrict__ xb, const short* __restrict__ h1b,
                       const short* __restrict__ h2b, const bf16* __restrict__ Bpack,
                       const void* __restrict__ bl, const int* __restrict__ flags,
                       void* __restrict__ out, int N) {
    bool fw = flags[1] != 0, fx = flags[0] != 0;
    int lane = threadIdx.x & 63, wave = threadIdx.x >> 6;
    int m = lane & 15, quad = lane >> 4;
    int r0 = blockIdx.x * 64 + wave * 16;
    if (r0 >= N) return;
    const short8* bp = (const short8*)Bpack;
    short8 B[14];
#pragma unroll
    for (int i = 0; i < 14; i++) B[i] = bp[i * 64 + lane];
    f32x4 acc0 = {0.f,0.f,0.f,0.f}, acc1 = {0.f,0.f,0.f,0.f};
    bool full = (r0 + 16 <= N);
    int row = r0 + m;
    bool rowok = full || (row < N);
#pragma unroll
    for (int s = 0; s < 7; s++) {
        short8 A = {0,0,0,0,0,0,0,0};
        if (rowok) {
            const short* p;
            if (s < 4)      p = &xb [(long long)row * 128 + s * 32 + quad * 8];
            else if (s < 6) p = &h1b[(long long)row * 64 + (s - 4) * 32 + quad * 8];
            else            p = &h2b[(long long)row * 32 + quad * 8];
            A = *(const short8*)p;
        }
        acc0 = MFMA16(A, B[s * 2 + 0], acc0);
        acc1 = MFMA16(A, B[s * 2 + 1], acc1);
    }
    float bl0 = ldf(bl, m, fw), bl1 = ldf(bl, m + 16, fw);
#pragma unroll
    for (int r = 0; r < 4; r++) {
        float v0 = acc0[r] + bl0, v1 = acc1[r] + bl1;
        float mx = fmaxf(v0, v1);
#pragma unroll
        for (int o = 8; o > 0; o >>= 1) mx = fmaxf(mx, __shfl_xor(mx, o));
        float sm = __expf(v0 - mx) + __expf(v1 - mx);
#pragma unroll
        for (int o = 8; o > 0; o >>= 1) sm += __shfl_xor(sm, o);
        float lse = mx + __logf(sm);
        int orow = r0 + quad * 4 + r;
        if (orow < N) {
            if (fx) {
                ((float*)out)[(long long)orow * 32 + m]      = v0 - lse;
                ((float*)out)[(long long)orow * 32 + 16 + m] = v1 - lse;
            } else {
                ((bf16*)out)[(long long)orow * 32 + m]      = __float2bfloat16(v0 - lse);
                ((bf16*)out)[(long long)orow * 32 + 16 + m] = __float2bfloat16(v1 - lse);
            }
        }
    }
}

extern "C" void kernel_launch(void* const* d_in, const int* in_sizes, int n_in,
                              void* d_out, int out_size, void* d_ws, size_t ws_size,
                              hipStream_t stream) {
    const void* x  = d_in[0];
    const int*  ei = (const int*)d_in[1];
    const void* W1 = d_in[2];
    const void* b1 = d_in[3];
    const void* W2 = d_in[4];
    const void* b2 = d_in[5];
    const void* Wl = d_in[6];
    const void* bl = d_in[7];

    int N = in_sizes[0] / 128;
    int E = in_sizes[1] / 2;

    // ws layout (4B units):
    // [flags 16 | counts N | cursor N | dinv N | rowptr N+16 | blocksums 4096 |
    //  Bp1 4096 | Bp2 1024 | Bp3 3584 | csr_src E | xb N*64 |
    //  A N*64 (h1x f32; later h2x f32 in [0,N*32), h2b bf16 in [N*48,N*64)) | h1b N*32]
    int* ip      = (int*)d_ws;
    int* flags   = ip;
    int* counts  = ip + 16;
    int* cursor  = counts + N;
    float* dinv  = (float*)(cursor + N);
    int* rowptr  = (int*)(dinv + N);
    int* blocksums = rowptr + N + 16;
    bf16* Bp1    = (bf16*)(blocksums + 4096);
    bf16* Bp2    = (bf16*)((int*)Bp1 + 4096);
    bf16* Bp3    = (bf16*)((int*)Bp2 + 1024);
    int* csr_src = (int*)Bp3 + 3584;
    short* xb    = (short*)(csr_src + E);                 // N*64 ints
    int*   Ai    = (int*)xb + (size_t)N * 64;             // region A: N*64 ints
    float* h1x   = (float*)Ai;
    float* h2x   = (float*)Ai;                            // alias (h1x dead after gather1)
    bf16*  h2b   = (bf16*)(Ai + (size_t)N * 48);          // upper quarter of A
    bf16*  h1b   = (bf16*)(Ai + (size_t)N * 64);          // N*32 ints

    hipMemsetAsync(ip, 0, (size_t)(16 + 2 * N) * sizeof(int), stream);

    sniff_kernel<<<3, 256, 0, stream>>>(x, W1, ei, E, flags);
    count_kernel<<<(E + 255) / 256, 256, 0, stream>>>(ei, E, flags, counts);
    dinv_kernel<<<(N + 255) / 256, 256, 0, stream>>>(counts, dinv, N);

    int nb = (N + 2047) / 2048;
    scan1_kernel<<<nb, 256, 0, stream>>>(counts, blocksums, N);
    scan2_kernel<<<1, 256, 0, stream>>>(blocksums, nb, rowptr, N, E);
    scan3_kernel<<<nb, 256, 0, stream>>>(counts, blocksums, rowptr, N);

    fill_kernel<<<(E + 255) / 256, 256, 0, stream>>>(ei, E, flags, rowptr, cursor, csr_src);
    repack_kernel<<<3, 256, 0, stream>>>(W1, W2, Wl, flags, Bp1, Bp2, Bp3);

    long long total8 = (long long)N * 16;   // groups of 8 elements of x
    cvt_x_kernel<<<(int)((total8 + 255) / 256), 256, 0, stream>>>(x, flags, xb, total8);

    gemm1_mfma_kernel<<<(N + 127) / 128, 256, 0, stream>>>(xb, Bp1, h1x, N);
    gather1_kernel<<<(N + 3) / 4, 256, 0, stream>>>(h1x, dinv, rowptr, csr_src, b1, flags, h1b, N);
    gemm2_mfma_kernel<<<(N + 63) / 64, 256, 0, stream>>>((const short*)h1b, Bp2, h2x, N);
    gather2_kernel<<<(N + 7) / 8, 256, 0, stream>>>(h2x, dinv, rowptr, csr_src, b2, flags, h2b, N);
    final_mfma_kernel<<<(N + 63) / 64, 256, 0, stream>>>(xb, (const short*)h1b, (const short*)h2b,
                                                         Bp3, bl, flags, d_out, N);
}

// Round 11
// 388.616 us; speedup vs baseline: 2.6275x; 1.3106x over previous
//
#include <hip/hip_runtime.h>
#include <hip/hip_bf16.h>

typedef __hip_bfloat16 bf16;
typedef __attribute__((ext_vector_type(8))) short short8;   // 8 bf16 (4 VGPRs)
typedef __attribute__((ext_vector_type(4))) float f32x4;    // MFMA accumulator

#define MFMA16(a, b, c) __builtin_amdgcn_mfma_f32_16x16x32_bf16((a), (b), (c), 0, 0, 0)

// dual-mode float load: f32 ? float buffer : bf16 buffer (same element index)
static __device__ __forceinline__ float ldf(const void* p, long long i, bool f32) {
    return f32 ? ((const float*)p)[i] : __bfloat162float(((const bf16*)p)[i]);
}

static __device__ __forceinline__ short f2bs(float v) {
    union { bf16 h; short s; } u; u.h = __float2bfloat16(v); return u.s;
}

// ---------------------------------------------------------------- encoding sniffer
// flags[0]: x is fp32?  flags[1]: weights are fp32?  flags[2]: edge_index is int64?
// MEASURED (R1 NaN-fail + R8 gating probe): this harness delivers x=fp32, W=fp32, out=fp32.
__global__ __launch_bounds__(256, 4)
void sniff_kernel(const void* __restrict__ x, const void* __restrict__ w,
                  const int* __restrict__ ei, int E, int* __restrict__ flags) {
    __shared__ int cnt;
    if (threadIdx.x == 0) cnt = 0;
    __syncthreads();
    if (blockIdx.x < 2) {
        const unsigned short* u = (const unsigned short*)(blockIdx.x == 0 ? x : w);
        int bad = 0;
        for (int i = threadIdx.x; i < 4096; i += 256) {
            unsigned e = (u[i] >> 7) & 0xFF;
            if (e >= 0xA0) bad++;
        }
        atomicAdd(&cnt, bad);
        __syncthreads();
        if (threadIdx.x == 0) flags[blockIdx.x] = (cnt > 16) ? 1 : 0;
    } else {
        int nz = 0;
        for (int i = threadIdx.x; i < 1024; i += 256)
            if (ei[2 * i + 1] != 0) nz++;
        atomicAdd(&cnt, nz);
        __syncthreads();
        if (threadIdx.x == 0) flags[2] = (cnt == 0) ? 1 : 0;
    }
}

static __device__ __forceinline__ int ld_src(const int* ei, int E, int e, bool i64) {
    return i64 ? ei[2 * e] : ei[e];
}
static __device__ __forceinline__ int ld_dst(const int* ei, int E, int e, bool i64) {
    return i64 ? ei[2 * (E + e)] : ei[E + e];
}

// ---------------------------------------------------------------- bucket CSR build
// shift=9: bucket b owns dst in [b*512, (b+1)*512). NB = ceil(N/512) <= 256.

// Pass A: global bucket histogram (LDS hist per block, 1 global add per bucket)
__global__ __launch_bounds__(256, 4)
void bhist_kernel(const int* __restrict__ ei, int E, const int* __restrict__ flags,
                  int shift, int NB, int* __restrict__ bucketCount) {
    __shared__ int h[256];
    for (int i = threadIdx.x; i < 256; i += 256) h[i] = 0;
    __syncthreads();
    bool i64 = flags[2] != 0;
    int base = blockIdx.x * 4096;
    for (int i = 0; i < 16; i++) {
        int e = base + i * 256 + threadIdx.x;
        if (e < E) atomicAdd(&h[ld_dst(ei, E, e, i64) >> shift], 1);
    }
    __syncthreads();
    for (int i = threadIdx.x; i < NB; i += 256)
        if (h[i]) atomicAdd(&bucketCount[i], h[i]);
}

// Pass B scan: bucketBase = exclusive scan; bcursor seeded with bases
__global__ __launch_bounds__(256, 4)
void bscan_kernel(const int* __restrict__ bucketCount, int NB,
                  int* __restrict__ bucketBase, int* __restrict__ bcursor, int E) {
    __shared__ int bs[256];
    int v = ((int)threadIdx.x < NB) ? bucketCount[threadIdx.x] : 0;
    bs[threadIdx.x] = v;
    __syncthreads();
    for (int off = 1; off < 256; off <<= 1) {
        int t = ((int)threadIdx.x >= off) ? bs[threadIdx.x - off] : 0;
        __syncthreads();
        bs[threadIdx.x] += t;
        __syncthreads();
    }
    int excl = bs[threadIdx.x] - v;
    if ((int)threadIdx.x < NB) { bucketBase[threadIdx.x] = excl; bcursor[threadIdx.x] = excl; }
    if (threadIdx.x == 0) bucketBase[NB] = E;
}

// Pass C: partition edges into bucket-contiguous ebuf (int2: x=src, y=dst)
__global__ __launch_bounds__(256, 4)
void bpart_kernel(const int* __restrict__ ei, int E, const int* __restrict__ flags,
                  int shift, int NB, int* __restrict__ bcursor, int2* __restrict__ ebuf) {
    __shared__ int h[256];
    __shared__ int gofs[256];
    for (int i = threadIdx.x; i < 256; i += 256) h[i] = 0;
    __syncthreads();
    bool i64 = flags[2] != 0;
    int base = blockIdx.x * 4096;
    // sweep 1: local histogram
    for (int i = 0; i < 16; i++) {
        int e = base + i * 256 + threadIdx.x;
        if (e < E) atomicAdd(&h[ld_dst(ei, E, e, i64) >> shift], 1);
    }
    __syncthreads();
    // claim contiguous global ranges (1 atomic per bucket per block)
    if ((int)threadIdx.x < NB) {
        int c = h[threadIdx.x];
        gofs[threadIdx.x] = c ? atomicAdd(&bcursor[threadIdx.x], c) : 0;
    }
    __syncthreads();
    for (int i = threadIdx.x; i < 256; i += 256) h[i] = 0;
    __syncthreads();
    // sweep 2: write edges into claimed dense runs
    for (int i = 0; i < 16; i++) {
        int e = base + i * 256 + threadIdx.x;
        if (e < E) {
            int s = ld_src(ei, E, e, i64), d = ld_dst(ei, E, e, i64);
            int b = d >> shift;
            int p = atomicAdd(&h[b], 1);
            ebuf[gofs[b] + p] = make_int2(s, d);
        }
    }
}

// Pass D: one block per bucket — local count, scan, rowptr+dinv write, csr fill.
// All csr writes land in one block's ~32KB window (single XCD L2; no line ping-pong).
__global__ __launch_bounds__(256, 2)
void bbuild_kernel(const int2* __restrict__ ebuf, const int* __restrict__ bucketBase,
                   int shift, int N, int E, int* __restrict__ rowptr,
                   float* __restrict__ dinv, int* __restrict__ csr_src) {
    __shared__ int cnt[1024];
    __shared__ int exc[1024];
    __shared__ int bs[256];
    int b = blockIdx.x;
    int nodeBase = b << shift;
    int width = 1 << shift;
    int nn = N - nodeBase; if (nn > width) nn = width;
    int beg = bucketBase[b], end = bucketBase[b + 1];
    for (int i = threadIdx.x; i < width; i += 256) cnt[i] = 0;
    __syncthreads();
    for (int e = beg + threadIdx.x; e < end; e += 256)
        atomicAdd(&cnt[ebuf[e].y - nodeBase], 1);
    __syncthreads();
    // exclusive scan of cnt[0..width)
    int per = width / 256;          // 2 at shift=9
    int s = 0;
    int base4 = threadIdx.x * per;
    for (int i = 0; i < per; i++) s += cnt[base4 + i];
    bs[threadIdx.x] = s;
    __syncthreads();
    for (int off = 1; off < 256; off <<= 1) {
        int t = ((int)threadIdx.x >= off) ? bs[threadIdx.x - off] : 0;
        __syncthreads();
        bs[threadIdx.x] += t;
        __syncthreads();
    }
    int run = bs[threadIdx.x] - s;
    for (int i = 0; i < per; i++) { exc[base4 + i] = run; run += cnt[base4 + i]; }
    __syncthreads();
    // rowptr + dinv (coalesced)
    for (int i = threadIdx.x; i < nn; i += 256) {
        int node = nodeBase + i;
        rowptr[node] = beg + exc[i];
        dinv[node] = rsqrtf((float)cnt[i] + 1.0f);
    }
    __syncthreads();
    for (int i = threadIdx.x; i < width; i += 256) cnt[i] = 0;
    __syncthreads();
    // csr fill within local window
    for (int e = beg + threadIdx.x; e < end; e += 256) {
        int2 v = ebuf[e];
        int l = v.y - nodeBase;
        int p = atomicAdd(&cnt[l], 1);
        csr_src[beg + exc[l] + p] = v.x;
    }
    if (b == 0 && threadIdx.x == 0) rowptr[N] = E;
}

// ---------------------------------------------------------------- weight -> MFMA B-fragment packs
// frag f = kstep*ntiles + ntile; slot s = f*64 + lane; element j (0..7):
//   W[kstep*32 + (lane>>4)*8 + j][ntile*16 + (lane&15)]  (fw-aware fp32/bf16 read)
__global__ __launch_bounds__(256, 4)
void repack_kernel(const void* __restrict__ W1, const void* __restrict__ W2,
                   const void* __restrict__ Wl, const int* __restrict__ flags,
                   bf16* __restrict__ Bp1, bf16* __restrict__ Bp2, bf16* __restrict__ Bp3) {
    bool fw = flags[1] != 0;
    const void* W; bf16* Bp; int ntiles, nc, nfrag;
    if (blockIdx.x == 0)      { W = W1; Bp = Bp1; ntiles = 4; nc = 64; nfrag = 16; }
    else if (blockIdx.x == 1) { W = W2; Bp = Bp2; ntiles = 2; nc = 32; nfrag = 4;  }
    else                      { W = Wl; Bp = Bp3; ntiles = 2; nc = 32; nfrag = 14; }
    for (int s = threadIdx.x; s < nfrag * 64; s += 256) {
        int f = s >> 6, lane = s & 63;
        int kstep = f / ntiles, ntile = f % ntiles;
        int n = ntile * 16 + (lane & 15);
        int kbase = kstep * 32 + (lane >> 4) * 8;
#pragma unroll
        for (int j = 0; j < 8; j++)
            Bp[s * 8 + j] = __float2bfloat16(ldf(W, (long long)(kbase + j) * nc + n, fw));
    }
}

// ---------------------------------------------------------------- x -> xb (bf16), both source dtypes
__global__ __launch_bounds__(256, 4)
void cvt_x_kernel(const void* __restrict__ x, const int* __restrict__ flags,
                  short* __restrict__ xb, long long total8) {
    long long i = (long long)blockIdx.x * 256 + threadIdx.x;
    if (i >= total8) return;
    bool fx = flags[0] != 0;
    short8 o;
    if (fx) {
        const float4* xf = (const float4*)x;
        float4 a = xf[i * 2], b = xf[i * 2 + 1];
        o[0] = f2bs(a.x); o[1] = f2bs(a.y); o[2] = f2bs(a.z); o[3] = f2bs(a.w);
        o[4] = f2bs(b.x); o[5] = f2bs(b.y); o[6] = f2bs(b.z); o[7] = f2bs(b.w);
    } else {
        o = ((const short8*)x)[i];
    }
    ((short8*)xb)[i] = o;
}

// ---------------------------------------------------------------- GEMM1 (MFMA): xb[N,128]@W1 -> h1x[N,64] f32
__global__ __launch_bounds__(256, 3)
void gemm1_mfma_kernel(const short* __restrict__ xb, const bf16* __restrict__ Bpack,
                       float* __restrict__ h1x, int N) {
    int lane = threadIdx.x & 63, wave = threadIdx.x >> 6;
    int m = lane & 15, quad = lane >> 4;
    int base = blockIdx.x * 128 + wave * 32;
    if (base >= N) return;
    const short8* bp = (const short8*)Bpack;
    short8 B[16];
#pragma unroll
    for (int i = 0; i < 16; i++) B[i] = bp[i * 64 + lane];
    if (base + 32 <= N) {
#pragma unroll
        for (int t = 0; t < 2; t++) {
            int r0 = base + t * 16;
            const short* xr = &xb[(long long)(r0 + m) * 128 + quad * 8];
            short8 A[4];
#pragma unroll
            for (int k = 0; k < 4; k++) A[k] = *(const short8*)(xr + k * 32);
            f32x4 acc[4];
#pragma unroll
            for (int nt = 0; nt < 4; nt++) acc[nt] = (f32x4){0.f, 0.f, 0.f, 0.f};
#pragma unroll
            for (int k = 0; k < 4; k++) {
#pragma unroll
                for (int nt = 0; nt < 4; nt++) acc[nt] = MFMA16(A[k], B[k * 4 + nt], acc[nt]);
            }
            // C/D: col = lane&15, row = quad*4 + r  [m89/m91]
            float* o = &h1x[(long long)(r0 + quad * 4) * 64 + m];
#pragma unroll
            for (int nt = 0; nt < 4; nt++) {
#pragma unroll
                for (int r = 0; r < 4; r++) o[(long long)r * 64 + nt * 16] = acc[nt][r];
            }
        }
    } else {
#pragma unroll
        for (int t = 0; t < 2; t++) {
            int r0 = base + t * 16;
            int row = r0 + m;
            short8 A[4];
#pragma unroll
            for (int k = 0; k < 4; k++) A[k] = (short8){0,0,0,0,0,0,0,0};
            if (row < N) {
                const short* xr = &xb[(long long)row * 128 + quad * 8];
#pragma unroll
                for (int k = 0; k < 4; k++) A[k] = *(const short8*)(xr + k * 32);
            }
            f32x4 acc[4];
#pragma unroll
            for (int nt = 0; nt < 4; nt++) acc[nt] = (f32x4){0.f, 0.f, 0.f, 0.f};
#pragma unroll
            for (int k = 0; k < 4; k++) {
#pragma unroll
                for (int nt = 0; nt < 4; nt++) acc[nt] = MFMA16(A[k], B[k * 4 + nt], acc[nt]);
            }
#pragma unroll
            for (int r = 0; r < 4; r++) {
                int orow = r0 + quad * 4 + r;
                if (orow < N) {
                    float* o = &h1x[(long long)orow * 64 + m];
#pragma unroll
                    for (int nt = 0; nt < 4; nt++) o[nt * 16] = acc[nt][r];
                }
            }
        }
    }
}

// ---------------------------------------------------------------- gather layer 1: one wave per node -> h1b (bf16)
__global__ __launch_bounds__(256, 4)
void gather1_kernel(const float* __restrict__ h1x, const float* __restrict__ dinv,
                    const int* __restrict__ rowptr, const int* __restrict__ csr_src,
                    const void* __restrict__ b1, const int* __restrict__ flags,
                    bf16* __restrict__ h1b, int N) {
    bool fw = flags[1] != 0;
    int lane = threadIdx.x & 63;
    int node = blockIdx.x * 4 + (threadIdx.x >> 6);
    if (node >= N) return;
    int beg = rowptr[node], end = rowptr[node + 1];
    float dvd = dinv[node];
    float acc = 0.f;
    for (int b = beg; b < end; b += 64) {
        int cnt = end - b; if (cnt > 64) cnt = 64;
        int s = 0; float dvs = 0.f;
        if (lane < cnt) { s = csr_src[b + lane]; dvs = dinv[s]; }
        for (int j = 0; j < cnt; j++) {
            int sj = __shfl(s, j);
            float nm = __shfl(dvs, j) * dvd;
            acc = fmaf(h1x[(long long)sj * 64 + lane], nm, acc);
        }
    }
    float v = acc + h1x[(long long)node * 64 + lane] * (dvd * dvd) + ldf(b1, lane, fw);
    h1b[(long long)node * 64 + lane] = __float2bfloat16(fmaxf(v, 0.f));
}

// ---------------------------------------------------------------- GEMM2 (MFMA): h1b[N,64]@W2 -> h2x[N,32] f32
__global__ __launch_bounds__(256, 4)
void gemm2_mfma_kernel(const short* __restrict__ h1b, const bf16* __restrict__ Bpack,
                       float* __restrict__ h2x, int N) {
    int lane = threadIdx.x & 63, wave = threadIdx.x >> 6;
    int m = lane & 15, quad = lane >> 4;
    int r0 = blockIdx.x * 64 + wave * 16;
    if (r0 >= N) return;
    const short8* bp = (const short8*)Bpack;
    short8 B[4];
#pragma unroll
    for (int i = 0; i < 4; i++) B[i] = bp[i * 64 + lane];
    f32x4 acc0 = {0.f,0.f,0.f,0.f}, acc1 = {0.f,0.f,0.f,0.f};
    if (r0 + 16 <= N) {
        const short* xr = &h1b[(long long)(r0 + m) * 64 + quad * 8];
#pragma unroll
        for (int k = 0; k < 2; k++) {
            short8 A = *(const short8*)(xr + k * 32);
            acc0 = MFMA16(A, B[k * 2 + 0], acc0);
            acc1 = MFMA16(A, B[k * 2 + 1], acc1);
        }
        float* o = &h2x[(long long)(r0 + quad * 4) * 32 + m];
#pragma unroll
        for (int r = 0; r < 4; r++) { o[(long long)r * 32] = acc0[r]; o[(long long)r * 32 + 16] = acc1[r]; }
    } else {
        int row = r0 + m;
#pragma unroll
        for (int k = 0; k < 2; k++) {
            short8 A = {0,0,0,0,0,0,0,0};
            if (row < N) A = *(const short8*)&h1b[(long long)row * 64 + k * 32 + quad * 8];
            acc0 = MFMA16(A, B[k * 2 + 0], acc0);
            acc1 = MFMA16(A, B[k * 2 + 1], acc1);
        }
#pragma unroll
        for (int r = 0; r < 4; r++) {
            int orow = r0 + quad * 4 + r;
            if (orow < N) {
                h2x[(long long)orow * 32 + m] = acc0[r];
                h2x[(long long)orow * 32 + 16 + m] = acc1[r];
            }
        }
    }
}

// ---------------------------------------------------------------- gather layer 2: h2x -> h2b (bf16)
__global__ __launch_bounds__(256, 4)
void gather2_kernel(const float* __restrict__ h2x, const float* __restrict__ dinv,
                    const int* __restrict__ rowptr, const int* __restrict__ csr_src,
                    const void* __restrict__ b2, const int* __restrict__ flags,
                    bf16* __restrict__ h2b, int N) {
    bool fw = flags[1] != 0;
    int j = threadIdx.x & 31;
    int node = blockIdx.x * 8 + (threadIdx.x >> 5);
    if (node >= N) return;
    int beg = rowptr[node], end = rowptr[node + 1];
    float dvd = dinv[node];
    float acc = 0.f;
    for (int b = beg; b < end; b += 32) {
        int cnt = end - b; if (cnt > 32) cnt = 32;
        int s = 0; float dvs = 0.f;
        if (j < cnt) { s = csr_src[b + j]; dvs = dinv[s]; }
        for (int jj = 0; jj < cnt; jj++) {
            int sj = __shfl(s, jj, 32);
            float nm = __shfl(dvs, jj, 32) * dvd;
            acc = fmaf(h2x[(long long)sj * 32 + j], nm, acc);
        }
    }
    acc += h2x[(long long)node * 32 + j] * (dvd * dvd) + ldf(b2, j, fw);
    h2b[(long long)node * 32 + j] = __float2bfloat16(acc);
}

// ---------------------------------------------------------------- final (MFMA): [xb|h1b|h2b]@Wl + bl -> log_softmax
__global__ __launch_bounds__(256, 2)
void final_mfma_kernel(const short* __restrict__ xb, const short* __restrict__ h1b,
                       const short* __restrict__ h2b, const bf16* __restrict__ Bpack,
                       const void* __restrict__ bl, const int* __restrict__ flags,
                       void* __restrict__ out, int N) {
    bool fw = flags[1] != 0, fx = flags[0] != 0;
    int lane = threadIdx.x & 63, wave = threadIdx.x >> 6;
    int m = lane & 15, quad = lane >> 4;
    int r0 = blockIdx.x * 64 + wave * 16;
    if (r0 >= N) return;
    const short8* bp = (const short8*)Bpack;
    short8 B[14];
#pragma unroll
    for (int i = 0; i < 14; i++) B[i] = bp[i * 64 + lane];
    f32x4 acc0 = {0.f,0.f,0.f,0.f}, acc1 = {0.f,0.f,0.f,0.f};
    bool full = (r0 + 16 <= N);
    int row = r0 + m;
    bool rowok = full || (row < N);
#pragma unroll
    for (int s = 0; s < 7; s++) {
        short8 A = {0,0,0,0,0,0,0,0};
        if (rowok) {
            const short* p;
            if (s < 4)      p = &xb [(long long)row * 128 + s * 32 + quad * 8];
            else if (s < 6) p = &h1b[(long long)row * 64 + (s - 4) * 32 + quad * 8];
            else            p = &h2b[(long long)row * 32 + quad * 8];
            A = *(const short8*)p;
        }
        acc0 = MFMA16(A, B[s * 2 + 0], acc0);
        acc1 = MFMA16(A, B[s * 2 + 1], acc1);
    }
    float bl0 = ldf(bl, m, fw), bl1 = ldf(bl, m + 16, fw);
#pragma unroll
    for (int r = 0; r < 4; r++) {
        float v0 = acc0[r] + bl0, v1 = acc1[r] + bl1;
        float mx = fmaxf(v0, v1);
#pragma unroll
        for (int o = 8; o > 0; o >>= 1) mx = fmaxf(mx, __shfl_xor(mx, o));
        float sm = __expf(v0 - mx) + __expf(v1 - mx);
#pragma unroll
        for (int o = 8; o > 0; o >>= 1) sm += __shfl_xor(sm, o);
        float lse = mx + __logf(sm);
        int orow = r0 + quad * 4 + r;
        if (orow < N) {
            if (fx) {
                ((float*)out)[(long long)orow * 32 + m]      = v0 - lse;
                ((float*)out)[(long long)orow * 32 + 16 + m] = v1 - lse;
            } else {
                ((bf16*)out)[(long long)orow * 32 + m]      = __float2bfloat16(v0 - lse);
                ((bf16*)out)[(long long)orow * 32 + 16 + m] = __float2bfloat16(v1 - lse);
            }
        }
    }
}

extern "C" void kernel_launch(void* const* d_in, const int* in_sizes, int n_in,
                              void* d_out, int out_size, void* d_ws, size_t ws_size,
                              hipStream_t stream) {
    const void* x  = d_in[0];
    const int*  ei = (const int*)d_in[1];
    const void* W1 = d_in[2];
    const void* b1 = d_in[3];
    const void* W2 = d_in[4];
    const void* b2 = d_in[5];
    const void* Wl = d_in[6];
    const void* bl = d_in[7];

    int N = in_sizes[0] / 128;
    int E = in_sizes[1] / 2;

    int shift = 9;
    while (((N + (1 << shift) - 1) >> shift) > 256 && shift < 10) shift++;
    int NB = (N + (1 << shift) - 1) >> shift;   // 196 at N=100k

    // ws layout (4B units):
    // [flags 16 | bucketCount 256 | bucketBase 272 | bcursor 256 | dinv N | rowptr N+16 |
    //  Bp1 4096 | Bp2 1024 | Bp3 3584 | csr_src E | xb N*64 |
    //  A N*64 (ebuf int2 E<=N*32; then h1x f32; later h2x f32 + h2b bf16) | h1b N*32]
    int* ip      = (int*)d_ws;
    int* flags   = ip;
    int* bucketCount = ip + 16;
    int* bucketBase  = bucketCount + 256;
    int* bcursor     = bucketBase + 272;
    float* dinv  = (float*)(bcursor + 256);
    int* rowptr  = (int*)(dinv + N);
    bf16* Bp1    = (bf16*)(rowptr + N + 16);
    bf16* Bp2    = (bf16*)((int*)Bp1 + 4096);
    bf16* Bp3    = (bf16*)((int*)Bp2 + 1024);
    int* csr_src = (int*)Bp3 + 3584;
    short* xb    = (short*)(csr_src + E);                 // N*64 ints
    int*   Ai    = (int*)xb + (size_t)N * 64;             // region A: N*64 ints
    int2*  ebuf  = (int2*)Ai;                             // E*2 ints (dead before gemm1)
    float* h1x   = (float*)Ai;
    float* h2x   = (float*)Ai;                            // alias (h1x dead after gather1)
    bf16*  h2b   = (bf16*)(Ai + (size_t)N * 48);          // upper quarter of A
    bf16*  h1b   = (bf16*)(Ai + (size_t)N * 64);          // N*32 ints

    // zero flags + bucketCount
    hipMemsetAsync(ip, 0, (16 + 256) * sizeof(int), stream);

    sniff_kernel<<<3, 256, 0, stream>>>(x, W1, ei, E, flags);

    int nchunk = (E + 4095) / 4096;
    bhist_kernel<<<nchunk, 256, 0, stream>>>(ei, E, flags, shift, NB, bucketCount);
    bscan_kernel<<<1, 256, 0, stream>>>(bucketCount, NB, bucketBase, bcursor, E);
    bpart_kernel<<<nchunk, 256, 0, stream>>>(ei, E, flags, shift, NB, bcursor, ebuf);
    bbuild_kernel<<<NB, 256, 0, stream>>>(ebuf, bucketBase, shift, N, E, rowptr, dinv, csr_src);

    repack_kernel<<<3, 256, 0, stream>>>(W1, W2, Wl, flags, Bp1, Bp2, Bp3);

    long long total8 = (long long)N * 16;   // groups of 8 elements of x
    cvt_x_kernel<<<(int)((total8 + 255) / 256), 256, 0, stream>>>(x, flags, xb, total8);

    gemm1_mfma_kernel<<<(N + 127) / 128, 256, 0, stream>>>(xb, Bp1, h1x, N);
    gather1_kernel<<<(N + 3) / 4, 256, 0, stream>>>(h1x, dinv, rowptr, csr_src, b1, flags, h1b, N);
    gemm2_mfma_kernel<<<(N + 63) / 64, 256, 0, stream>>>((const short*)h1b, Bp2, h2x, N);
    gather2_kernel<<<(N + 7) / 8, 256, 0, stream>>>(h2x, dinv, rowptr, csr_src, b2, flags, h2b, N);
    final_mfma_kernel<<<(N + 63) / 64, 256, 0, stream>>>(xb, (const short*)h1b, (const short*)h2b,
                                                         Bp3, bl, flags, d_out, N);
}